// Round 1
// baseline (10.800 us; speedup 1.0000x reference)
//
#include <hip/hip_runtime.h>
#include <hip/hip_bf16.h>

// out[b,u] = tanh( sum_f inputs[b, T-1, f] * kernel[f,u] + bias[u] )
// B=256, T=512, F=256, U=256, all fp32.
//
// One block per b (256 blocks), 256 threads = one per u.
// x-row staged in LDS (broadcast reads, no bank conflicts).
// kernel[f*U + u] reads are fully coalesced across the u-threads and the
// 256 KB kernel matrix is L2-resident after first touch.

#define B_DIM 256
#define T_DIM 512
#define F_DIM 256
#define U_DIM 256

__global__ __launch_bounds__(256) void lastslice_matmul_tanh(
    const float* __restrict__ inputs,   // [B, T, F]
    const float* __restrict__ kern,     // [F, U]
    const float* __restrict__ bias,     // [U]
    float* __restrict__ out)            // [B, U]
{
    const int b = blockIdx.x;
    const int u = threadIdx.x;

    __shared__ float xs[F_DIM];

    // last-timestep row of this batch element
    const float* xrow = inputs + ((size_t)b * T_DIM + (T_DIM - 1)) * F_DIM;
    xs[u] = xrow[u];          // 256 threads load 256 floats, coalesced
    __syncthreads();

    float acc = bias[u];
    #pragma unroll 8
    for (int f = 0; f < F_DIM; ++f) {
        acc = fmaf(xs[f], kern[f * U_DIM + u], acc);
    }

    out[b * U_DIM + u] = tanhf(acc);
}

extern "C" void kernel_launch(void* const* d_in, const int* in_sizes, int n_in,
                              void* d_out, int out_size, void* d_ws, size_t ws_size,
                              hipStream_t stream) {
    const float* inputs = (const float*)d_in[0];   // B*T*F
    const float* kern   = (const float*)d_in[1];   // F*U
    const float* bias   = (const float*)d_in[2];   // U
    float* out          = (float*)d_out;           // B*U

    dim3 grid(B_DIM);
    dim3 block(U_DIM);
    lastslice_matmul_tanh<<<grid, block, 0, stream>>>(inputs, kern, bias, out);
}